// Round 2
// baseline (1203.358 us; speedup 1.0000x reference)
//
#include <hip/hip_runtime.h>
#include <cmath>

// Problem constants (match reference setup_inputs)
#define NN 50000
#define EE 800000
#define ET (EE + NN)   // edges + self loops
#define IN_DIM 256
#define HID 72

// ---------------------------------------------------------------------------
// CSR construction: histogram -> scan -> scatter
// ---------------------------------------------------------------------------
__global__ void hist_kernel(const int* __restrict__ ei, int* __restrict__ deg) {
    int i = blockIdx.x * blockDim.x + threadIdx.x;
    if (i >= ET) return;
    int dst = (i < EE) ? ei[EE + i] : (i - EE);
    atomicAdd(&deg[dst], 1);
}

__global__ void scan_kernel(const int* __restrict__ deg, int* __restrict__ rowptr, int n) {
    __shared__ int sh[1024];
    __shared__ int carry;
    int tid = threadIdx.x;
    if (tid == 0) { carry = 0; rowptr[0] = 0; }
    __syncthreads();
    for (int base = 0; base < n; base += 1024) {
        int i = base + tid;
        int v = (i < n) ? deg[i] : 0;
        sh[tid] = v;
        __syncthreads();
        for (int off = 1; off < 1024; off <<= 1) {
            int t = (tid >= off) ? sh[tid - off] : 0;
            __syncthreads();
            sh[tid] += t;
            __syncthreads();
        }
        if (i < n) rowptr[i + 1] = sh[tid] + carry;
        __syncthreads();
        if (tid == 0) carry += sh[1023];
        __syncthreads();
    }
}

__global__ void scatter_kernel(const int* __restrict__ ei, const int* __restrict__ rowptr,
                               int* __restrict__ cursor, int* __restrict__ csr) {
    int i = blockIdx.x * blockDim.x + threadIdx.x;
    if (i >= ET) return;
    int src = (i < EE) ? ei[i] : (i - EE);
    int dst = (i < EE) ? ei[EE + i] : (i - EE);
    int pos = atomicAdd(&cursor[dst], 1);
    csr[rowptr[dst] + pos] = src;
}

// ---------------------------------------------------------------------------
// Tiled fp32 GEMM: C[M,Nfull] = A[M,K] @ B[K,Nfull] (+bias), 72-col tiles
// BM=128 rows/block, 256 threads; thread (trow=tid&31, tcol=tid>>5)
// computes rows {trow+32*i, i<4} x cols {tcol*9+j, j<9}.
// ---------------------------------------------------------------------------
#define BM 128
#define BK 32
__global__ __launch_bounds__(256) void gemm_tile72(
        const float* __restrict__ A, const float* __restrict__ B,
        const float* __restrict__ bias, float* __restrict__ C,
        int M, int K, int Nfull) {
    __shared__ float As[BK][BM + 1];  // +1 pad: conflict-free store & load
    __shared__ float Bs[BK][72];
    int row0 = blockIdx.x * BM;
    int col0 = blockIdx.y * 72;
    int tid = threadIdx.x;
    int trow = tid & 31;
    int tcol = tid >> 5;
    float acc[4][9];
    #pragma unroll
    for (int i = 0; i < 4; ++i)
        #pragma unroll
        for (int j = 0; j < 9; ++j) acc[i][j] = 0.f;

    for (int k0 = 0; k0 < K; k0 += BK) {
        // stage A tile (coalesced along K)
        #pragma unroll
        for (int idx = tid; idx < BM * BK; idx += 256) {
            int r = idx / BK, kk = idx % BK;
            int gr = row0 + r, gk = k0 + kk;
            As[kk][r] = (gr < M && gk < K) ? A[(size_t)gr * K + gk] : 0.f;
        }
        // stage B tile
        #pragma unroll
        for (int idx = tid; idx < BK * 72; idx += 256) {
            int kk = idx / 72, c = idx % 72;
            int gk = k0 + kk;
            Bs[kk][c] = (gk < K) ? B[(size_t)gk * Nfull + col0 + c] : 0.f;
        }
        __syncthreads();
        #pragma unroll 4
        for (int kk = 0; kk < BK; ++kk) {
            float a[4], b[9];
            #pragma unroll
            for (int i = 0; i < 4; ++i) a[i] = As[kk][trow + 32 * i];
            #pragma unroll
            for (int j = 0; j < 9; ++j) b[j] = Bs[kk][tcol * 9 + j];
            #pragma unroll
            for (int i = 0; i < 4; ++i)
                #pragma unroll
                for (int j = 0; j < 9; ++j)
                    acc[i][j] = fmaf(a[i], b[j], acc[i][j]);
        }
        __syncthreads();
    }
    #pragma unroll
    for (int i = 0; i < 4; ++i) {
        int gr = row0 + trow + 32 * i;
        if (gr >= M) continue;
        #pragma unroll
        for (int j = 0; j < 9; ++j) {
            int c = col0 + tcol * 9 + j;
            float v = acc[i][j] + (bias ? bias[c] : 0.f);
            C[(size_t)gr * Nfull + c] = v;
        }
    }
}

// ---------------------------------------------------------------------------
// Per-node attention logits: ls[n,h] = <hp[n,h,:], a_src[h,:]>, ld likewise.
// One wave per node.
// ---------------------------------------------------------------------------
template <int H, int C>
__global__ void logits_kernel(const float* __restrict__ hp,
                              const float* __restrict__ a_src, const float* __restrict__ a_dst,
                              float* __restrict__ ls, float* __restrict__ ld, int n) {
    int wid = (blockIdx.x * blockDim.x + threadIdx.x) >> 6;
    int lane = threadIdx.x & 63;
    if (wid >= n) return;
    const float* row = hp + (size_t)wid * (H * C);
    #pragma unroll
    for (int h = 0; h < H; ++h) {
        float vs = 0.f, vd = 0.f;
        for (int c = lane; c < C; c += 64) {
            float x = row[h * C + c];
            vs += x * a_src[h * C + c];
            vd += x * a_dst[h * C + c];
        }
        #pragma unroll
        for (int off = 32; off; off >>= 1) {
            vs += __shfl_xor(vs, off);
            vd += __shfl_xor(vd, off);
        }
        if (lane == 0) { ls[wid * H + h] = vs; ld[wid * H + h] = vd; }
    }
}

// ---------------------------------------------------------------------------
// GAT aggregation, one wave (block of 64) per destination node.
// 3 passes over incoming edges: max, sum-exp, weighted gather.
// Epilogue: +bias, ELU, optional residual add.
// ---------------------------------------------------------------------------
template <int H, int C, bool ADD_RES>
__global__ __launch_bounds__(64) void agg_kernel(
        const float* __restrict__ hp, const float* __restrict__ ls, const float* __restrict__ ld,
        const int* __restrict__ rowptr, const int* __restrict__ csr,
        const float* __restrict__ bias, const float* __restrict__ res,
        float* __restrict__ out, int n) {
    constexpr int CH = H * C;
    constexpr int CPT = (CH + 63) / 64;
    __shared__ float wsh[64 * H];
    __shared__ int ssh[64];
    int wid = blockIdx.x;
    int lane = threadIdx.x;
    if (wid >= n) return;
    int rp0 = rowptr[wid], rp1 = rowptr[wid + 1];

    float ldh[H];
    #pragma unroll
    for (int h = 0; h < H; ++h) ldh[h] = ld[wid * H + h];

    // pass 1: per-head max of leaky-relu logits
    float m[H];
    #pragma unroll
    for (int h = 0; h < H; ++h) m[h] = -__builtin_inff();
    for (int i = rp0 + lane; i < rp1; i += 64) {
        int s = csr[i];
        #pragma unroll
        for (int h = 0; h < H; ++h) {
            float e = ls[s * H + h] + ldh[h];
            e = (e > 0.f) ? e : 0.2f * e;
            m[h] = fmaxf(m[h], e);
        }
    }
    #pragma unroll
    for (int h = 0; h < H; ++h)
        #pragma unroll
        for (int off = 32; off; off >>= 1) m[h] = fmaxf(m[h], __shfl_xor(m[h], off));

    // pass 2: sum of exp
    float ssum[H];
    #pragma unroll
    for (int h = 0; h < H; ++h) ssum[h] = 0.f;
    for (int i = rp0 + lane; i < rp1; i += 64) {
        int s = csr[i];
        #pragma unroll
        for (int h = 0; h < H; ++h) {
            float e = ls[s * H + h] + ldh[h];
            e = (e > 0.f) ? e : 0.2f * e;
            ssum[h] += expf(e - m[h]);
        }
    }
    #pragma unroll
    for (int h = 0; h < H; ++h)
        #pragma unroll
        for (int off = 32; off; off >>= 1) ssum[h] += __shfl_xor(ssum[h], off);
    float inv[H];
    #pragma unroll
    for (int h = 0; h < H; ++h) inv[h] = 1.f / fmaxf(ssum[h], 1e-16f);

    // pass 3: weighted gather-aggregate
    float acc[CPT];
    #pragma unroll
    for (int k = 0; k < CPT; ++k) acc[k] = 0.f;
    int heads[CPT];
    #pragma unroll
    for (int k = 0; k < CPT; ++k) heads[k] = (lane + 64 * k) / C;

    for (int base = rp0; base < rp1; base += 64) {
        int i = base + lane;
        int lim = min(64, rp1 - base);
        if (i < rp1) {
            int s = csr[i];
            ssh[lane] = s;
            #pragma unroll
            for (int h = 0; h < H; ++h) {
                float e = ls[s * H + h] + ldh[h];
                e = (e > 0.f) ? e : 0.2f * e;
                wsh[lane * H + h] = expf(e - m[h]) * inv[h];
            }
        }
        __syncthreads();
        for (int t = 0; t < lim; ++t) {
            int s = ssh[t];
            const float* rowp = hp + (size_t)s * CH;
            #pragma unroll
            for (int k = 0; k < CPT; ++k) {
                int ch = lane + 64 * k;
                if (ch < CH) acc[k] = fmaf(wsh[t * H + heads[k]], rowp[ch], acc[k]);
            }
        }
        __syncthreads();
    }

    // epilogue: bias + ELU (+ residual)
    #pragma unroll
    for (int k = 0; k < CPT; ++k) {
        int ch = lane + 64 * k;
        if (ch < CH) {
            float v = acc[k] + bias[ch];
            v = (v > 0.f) ? v : expm1f(v);
            if (ADD_RES) v += res[(size_t)wid * CH + ch];
            out[(size_t)wid * CH + ch] = v;
        }
    }
}

// ---------------------------------------------------------------------------
// Score MLP: out[n] = relu(h[n,:]@Ws1 + bs1) @ Ws2 + bs2.  32 lanes / node.
// ---------------------------------------------------------------------------
__global__ __launch_bounds__(256) void score_kernel(
        const float* __restrict__ h, const float* __restrict__ Ws1, const float* __restrict__ bs1,
        const float* __restrict__ Ws2, const float* __restrict__ bs2,
        float* __restrict__ out, int n) {
    int sub = threadIdx.x >> 5;            // 8 nodes per block
    int j = threadIdx.x & 31;              // hidden unit
    int node = blockIdx.x * 8 + sub;
    if (node >= n) return;
    const float* row = h + (size_t)node * HID;
    float acc = bs1[j];
    #pragma unroll 8
    for (int c = 0; c < HID; ++c) acc = fmaf(row[c], Ws1[c * 32 + j], acc);
    float v = fmaxf(acc, 0.f) * Ws2[j];
    #pragma unroll
    for (int off = 16; off; off >>= 1) v += __shfl_down(v, off, 32);
    if (j == 0) out[node] = v + bs2[0];
}

// ---------------------------------------------------------------------------
extern "C" void kernel_launch(void* const* d_in, const int* in_sizes, int n_in,
                              void* d_out, int out_size, void* d_ws, size_t ws_size,
                              hipStream_t stream) {
    const float* x      = (const float*)d_in[0];
    const int*   ei     = (const int*)  d_in[1];
    const float* W_in   = (const float*)d_in[2];
    const float* b_in   = (const float*)d_in[3];
    const float* W1     = (const float*)d_in[4];
    const float* a_src1 = (const float*)d_in[5];
    const float* a_dst1 = (const float*)d_in[6];
    const float* b1     = (const float*)d_in[7];
    const float* W2     = (const float*)d_in[8];
    const float* a_src2 = (const float*)d_in[9];
    const float* a_dst2 = (const float*)d_in[10];
    const float* b2     = (const float*)d_in[11];
    const float* W3     = (const float*)d_in[12];
    const float* a_src3 = (const float*)d_in[13];
    const float* a_dst3 = (const float*)d_in[14];
    const float* b3     = (const float*)d_in[15];
    const float* Ws1    = (const float*)d_in[16];
    const float* bs1    = (const float*)d_in[17];
    const float* Ws2    = (const float*)d_in[18];
    const float* bs2    = (const float*)d_in[19];
    float* out = (float*)d_out;

    // workspace carve-up (floats/ints, all 4-byte)
    float* ws   = (float*)d_ws;
    float* x0   = ws;                       // N*72
    float* bufA = x0 + (size_t)NN * HID;    // N*288 (hp1/hp2/hp3)
    float* bufB = bufA + (size_t)NN * 288;  // N*288 (h1/h2/h3)
    float* ls   = bufB + (size_t)NN * 288;  // N*4
    float* ld   = ls + (size_t)NN * 4;      // N*4
    int* deg    = (int*)(ld + (size_t)NN * 4);
    int* rowptr = deg + NN;                 // N+1
    int* cursor = rowptr + NN + 1;          // N
    int* csr    = cursor + NN;              // ET

    hipMemsetAsync(deg, 0, NN * sizeof(int), stream);
    hipMemsetAsync(cursor, 0, NN * sizeof(int), stream);

    const int egrid = (ET + 255) / 256;
    hist_kernel<<<egrid, 256, 0, stream>>>(ei, deg);
    scan_kernel<<<1, 1024, 0, stream>>>(deg, rowptr, NN);
    scatter_kernel<<<egrid, 256, 0, stream>>>(ei, rowptr, cursor, csr);

    const int mblocks = (NN + BM - 1) / BM;  // 391
    // x0 = x @ W_in + b_in
    gemm_tile72<<<dim3(mblocks, 1), 256, 0, stream>>>(x, W_in, b_in, x0, NN, IN_DIM, HID);
    // layer 1: hp1 = x0 @ W1 [N,288]
    gemm_tile72<<<dim3(mblocks, 4), 256, 0, stream>>>(x0, W1, nullptr, bufA, NN, HID, 288);
    logits_kernel<4, 72><<<(NN + 3) / 4, 256, 0, stream>>>(bufA, a_src1, a_dst1, ls, ld, NN);
    agg_kernel<4, 72, false><<<NN, 64, 0, stream>>>(bufA, ls, ld, rowptr, csr, b1, nullptr, bufB, NN);
    // layer 2: hp2 = h1 @ W2 [N,72]
    gemm_tile72<<<dim3(mblocks, 1), 256, 0, stream>>>(bufB, W2, nullptr, bufA, NN, 288, HID);
    logits_kernel<1, 72><<<(NN + 3) / 4, 256, 0, stream>>>(bufA, a_src2, a_dst2, ls, ld, NN);
    agg_kernel<1, 72, false><<<NN, 64, 0, stream>>>(bufA, ls, ld, rowptr, csr, b2, nullptr, bufB, NN);
    // layer 3: hp3 = h2 @ W3 [N,72]
    gemm_tile72<<<dim3(mblocks, 1), 256, 0, stream>>>(bufB, W3, nullptr, bufA, NN, HID, HID);
    logits_kernel<1, 72><<<(NN + 3) / 4, 256, 0, stream>>>(bufA, a_src3, a_dst3, ls, ld, NN);
    agg_kernel<1, 72, true><<<NN, 64, 0, stream>>>(bufA, ls, ld, rowptr, csr, b3, x0, bufB, NN);
    // score head
    score_kernel<<<(NN + 7) / 8, 256, 0, stream>>>(bufB, Ws1, bs1, Ws2, bs2, out, NN);
}

// Round 3
// 842.025 us; speedup vs baseline: 1.4291x; 1.4291x over previous
//
#include <hip/hip_runtime.h>
#include <cmath>

// Problem constants (match reference setup_inputs)
#define NN 50000
#define EE 800000
#define ET (EE + NN)   // edges + self loops
#define IN_DIM 256
#define HID 72

// ---------------------------------------------------------------------------
// CSR construction: histogram -> hierarchical scan -> scatter
// ---------------------------------------------------------------------------
__global__ void hist_kernel(const int* __restrict__ ei, int* __restrict__ deg) {
    int i = blockIdx.x * blockDim.x + threadIdx.x;
    if (i >= ET) return;
    int dst = (i < EE) ? ei[EE + i] : (i - EE);
    atomicAdd(&deg[dst], 1);
}

// stage 1: per-block inclusive scan of 256 elems + block sums
__global__ __launch_bounds__(256) void scan1_kernel(const int* __restrict__ deg,
        int* __restrict__ tmp, int* __restrict__ bsum, int n) {
    __shared__ int sh[256];
    int tid = threadIdx.x;
    int i = blockIdx.x * 256 + tid;
    sh[tid] = (i < n) ? deg[i] : 0;
    __syncthreads();
    for (int off = 1; off < 256; off <<= 1) {
        int t = (tid >= off) ? sh[tid - off] : 0;
        __syncthreads();
        sh[tid] += t;
        __syncthreads();
    }
    if (i < n) tmp[i] = sh[tid];
    if (tid == 255) bsum[blockIdx.x] = sh[255];
}

// stage 2: scan the (<=256) block sums in one block
__global__ __launch_bounds__(256) void scan2_kernel(int* __restrict__ bsum, int nb) {
    __shared__ int sh[256];
    int tid = threadIdx.x;
    sh[tid] = (tid < nb) ? bsum[tid] : 0;
    __syncthreads();
    for (int off = 1; off < 256; off <<= 1) {
        int t = (tid >= off) ? sh[tid - off] : 0;
        __syncthreads();
        sh[tid] += t;
        __syncthreads();
    }
    if (tid < nb) bsum[tid] = sh[tid];
}

// stage 3: add block offsets, emit rowptr
__global__ __launch_bounds__(256) void scan3_kernel(const int* __restrict__ tmp,
        const int* __restrict__ bsum, int* __restrict__ rowptr, int n) {
    int i = blockIdx.x * 256 + threadIdx.x;
    if (i == 0) rowptr[0] = 0;
    if (i < n) {
        int off = (blockIdx.x > 0) ? bsum[blockIdx.x - 1] : 0;
        rowptr[i + 1] = tmp[i] + off;
    }
}

__global__ void scatter_kernel(const int* __restrict__ ei, const int* __restrict__ rowptr,
                               int* __restrict__ cursor, int* __restrict__ csr) {
    int i = blockIdx.x * blockDim.x + threadIdx.x;
    if (i >= ET) return;
    int src = (i < EE) ? ei[i] : (i - EE);
    int dst = (i < EE) ? ei[EE + i] : (i - EE);
    int pos = atomicAdd(&cursor[dst], 1);
    csr[rowptr[dst] + pos] = src;
}

// ---------------------------------------------------------------------------
// Projected attention vectors for layer 1:
// wsrc[h][k] = sum_c W1[k, h*72+c] * a_src1[h,c]   (so logit_s = x0 . wsrc[h])
// ---------------------------------------------------------------------------
__global__ void attnproj_kernel(const float* __restrict__ W1,
                                const float* __restrict__ a_src, const float* __restrict__ a_dst,
                                float* __restrict__ wsrc, float* __restrict__ wdst) {
    int j = blockIdx.x * blockDim.x + threadIdx.x;   // j = h*72 + k
    if (j >= 4 * HID) return;
    int h = j / HID, k = j % HID;
    const float* wrow = W1 + (size_t)k * (4 * HID) + h * HID;
    const float* as = a_src + h * HID;
    const float* ad = a_dst + h * HID;
    float s = 0.f, d = 0.f;
    for (int c = 0; c < HID; ++c) {
        float w = wrow[c];
        s = fmaf(w, as[c], s);
        d = fmaf(w, ad[c], d);
    }
    wsrc[j] = s;
    wdst[j] = d;
}

// ---------------------------------------------------------------------------
// Tiled fp32 GEMM: C[M,Nfull] = A[M,K(+off)] @ B[K,Nfull] (+bias)(+ELU)
// BATCHED_A: A column block follows blockIdx.y (head-block-diagonal product).
// ---------------------------------------------------------------------------
#define BM 128
#define BK 32
template <bool BATCHED_A, bool ELU_EPI>
__global__ __launch_bounds__(256) void gemm_tile72(
        const float* __restrict__ A, const float* __restrict__ B,
        const float* __restrict__ bias, float* __restrict__ C,
        int M, int K, int lda, int Nfull) {
    __shared__ float As[BK][BM + 1];
    __shared__ float Bs[BK][72];
    int row0 = blockIdx.x * BM;
    int col0 = blockIdx.y * 72;
    int aoff = BATCHED_A ? col0 : 0;
    int tid = threadIdx.x;
    int trow = tid & 31;
    int tcol = tid >> 5;
    float acc[4][9];
    #pragma unroll
    for (int i = 0; i < 4; ++i)
        #pragma unroll
        for (int j = 0; j < 9; ++j) acc[i][j] = 0.f;

    for (int k0 = 0; k0 < K; k0 += BK) {
        #pragma unroll
        for (int idx = tid; idx < BM * BK; idx += 256) {
            int r = idx / BK, kk = idx % BK;
            int gr = row0 + r, gk = k0 + kk;
            As[kk][r] = (gr < M && gk < K) ? A[(size_t)gr * lda + aoff + gk] : 0.f;
        }
        #pragma unroll
        for (int idx = tid; idx < BK * 72; idx += 256) {
            int kk = idx / 72, c = idx % 72;
            int gk = k0 + kk;
            Bs[kk][c] = (gk < K) ? B[(size_t)gk * Nfull + col0 + c] : 0.f;
        }
        __syncthreads();
        #pragma unroll 4
        for (int kk = 0; kk < BK; ++kk) {
            float a[4], b[9];
            #pragma unroll
            for (int i = 0; i < 4; ++i) a[i] = As[kk][trow + 32 * i];
            #pragma unroll
            for (int j = 0; j < 9; ++j) b[j] = Bs[kk][tcol * 9 + j];
            #pragma unroll
            for (int i = 0; i < 4; ++i)
                #pragma unroll
                for (int j = 0; j < 9; ++j)
                    acc[i][j] = fmaf(a[i], b[j], acc[i][j]);
        }
        __syncthreads();
    }
    #pragma unroll
    for (int i = 0; i < 4; ++i) {
        int gr = row0 + trow + 32 * i;
        if (gr >= M) continue;
        #pragma unroll
        for (int j = 0; j < 9; ++j) {
            int c = col0 + tcol * 9 + j;
            float v = acc[i][j] + (bias ? bias[c] : 0.f);
            if (ELU_EPI) v = (v > 0.f) ? v : expm1f(v);
            C[(size_t)gr * Nfull + c] = v;
        }
    }
}

// ---------------------------------------------------------------------------
// Layer-1 logits from x0 and projected attention vectors. One wave per node.
// ---------------------------------------------------------------------------
__global__ __launch_bounds__(64) void logits1_kernel(const float* __restrict__ x0,
        const float* __restrict__ wsrc, const float* __restrict__ wdst,
        float* __restrict__ ls, float* __restrict__ ld, int n) {
    int wid = blockIdx.x;
    int lane = threadIdx.x;
    if (wid >= n) return;
    const float* row = x0 + (size_t)wid * HID;
    float xa = row[lane];
    float xb = (lane < 8) ? row[64 + lane] : 0.f;
    #pragma unroll
    for (int h = 0; h < 4; ++h) {
        float vs = xa * wsrc[h * HID + lane];
        float vd = xa * wdst[h * HID + lane];
        if (lane < 8) {
            vs = fmaf(xb, wsrc[h * HID + 64 + lane], vs);
            vd = fmaf(xb, wdst[h * HID + 64 + lane], vd);
        }
        #pragma unroll
        for (int off = 32; off; off >>= 1) {
            vs += __shfl_xor(vs, off);
            vd += __shfl_xor(vd, off);
        }
        if (lane == 0) { ls[wid * 4 + h] = vs; ld[wid * 4 + h] = vd; }
    }
}

// Layers 2/3 logits: ls/ld[n] = <hp[n,:], a_src/a_dst>. 4 nodes per 256-block.
__global__ void logits_hp_kernel(const float* __restrict__ hp,
                                 const float* __restrict__ a_src, const float* __restrict__ a_dst,
                                 float* __restrict__ ls, float* __restrict__ ld, int n) {
    int wid = (blockIdx.x * blockDim.x + threadIdx.x) >> 6;
    int lane = threadIdx.x & 63;
    if (wid >= n) return;
    const float* row = hp + (size_t)wid * HID;
    float xa = row[lane];
    float xb = (lane < 8) ? row[64 + lane] : 0.f;
    float vs = xa * a_src[lane];
    float vd = xa * a_dst[lane];
    if (lane < 8) {
        vs = fmaf(xb, a_src[64 + lane], vs);
        vd = fmaf(xb, a_dst[64 + lane], vd);
    }
    #pragma unroll
    for (int off = 32; off; off >>= 1) {
        vs += __shfl_xor(vs, off);
        vd += __shfl_xor(vd, off);
    }
    if (lane == 0) { ls[wid] = vs; ld[wid] = vd; }
}

// ---------------------------------------------------------------------------
// Softmax-weighted gather of 72-wide feature rows; one wave per dst node.
// H heads share the same gathered row (layer 1: H=4, raw out; layers 2/3:
// H=1 with bias+ELU(+residual) epilogue).
// ---------------------------------------------------------------------------
template <int H, bool EPI, bool ADD_RES>
__global__ __launch_bounds__(64) void agg_gather(
        const float* __restrict__ feat, const float* __restrict__ ls, const float* __restrict__ ld,
        const int* __restrict__ rowptr, const int* __restrict__ csr,
        const float* __restrict__ bias, const float* __restrict__ res,
        float* __restrict__ out, int n) {
    __shared__ float wsh[64 * H];
    __shared__ int ssh[64];
    int wid = blockIdx.x;
    int lane = threadIdx.x;
    if (wid >= n) return;
    int rp0 = rowptr[wid], rp1 = rowptr[wid + 1];
    bool small = (rp1 - rp0) <= 64;

    float ldh[H];
    if (H == 4) {
        float4 t = ((const float4*)ld)[wid];
        ldh[0] = t.x; ldh[1] = t.y; ldh[2] = t.z; ldh[3] = t.w;
    } else {
        ldh[0] = ld[wid];
    }

    // pass 1: per-head max of leaky-relu logits
    float m[H];
    #pragma unroll
    for (int h = 0; h < H; ++h) m[h] = -__builtin_inff();
    for (int i = rp0 + lane; i < rp1; i += 64) {
        int s = csr[i];
        float e[H];
        if (H == 4) {
            float4 lv = ((const float4*)ls)[s];
            e[0] = lv.x; e[1] = lv.y; e[2] = lv.z; e[3] = lv.w;
        } else {
            e[0] = ls[s];
        }
        #pragma unroll
        for (int h = 0; h < H; ++h) {
            float v = e[h] + ldh[h];
            v = (v > 0.f) ? v : 0.2f * v;
            m[h] = fmaxf(m[h], v);
        }
    }
    #pragma unroll
    for (int h = 0; h < H; ++h)
        #pragma unroll
        for (int off = 32; off; off >>= 1) m[h] = fmaxf(m[h], __shfl_xor(m[h], off));

    // pass 2: sum of exp (stash per-edge p for the common deg<=64 case)
    float ssum[H];
    #pragma unroll
    for (int h = 0; h < H; ++h) ssum[h] = 0.f;
    for (int i = rp0 + lane; i < rp1; i += 64) {
        int s = csr[i];
        float e[H];
        if (H == 4) {
            float4 lv = ((const float4*)ls)[s];
            e[0] = lv.x; e[1] = lv.y; e[2] = lv.z; e[3] = lv.w;
        } else {
            e[0] = ls[s];
        }
        #pragma unroll
        for (int h = 0; h < H; ++h) {
            float v = e[h] + ldh[h];
            v = (v > 0.f) ? v : 0.2f * v;
            float p = expf(v - m[h]);
            ssum[h] += p;
            wsh[lane * H + h] = p;
        }
    }
    #pragma unroll
    for (int h = 0; h < H; ++h)
        #pragma unroll
        for (int off = 32; off; off >>= 1) ssum[h] += __shfl_xor(ssum[h], off);
    float inv[H];
    #pragma unroll
    for (int h = 0; h < H; ++h) inv[h] = 1.f / fmaxf(ssum[h], 1e-16f);

    if (small && rp0 + lane < rp1) {
        #pragma unroll
        for (int h = 0; h < H; ++h) wsh[lane * H + h] *= inv[h];
    }

    // pass 3: weighted gather (2-edge unroll for latency overlap)
    float acc[H][2];
    #pragma unroll
    for (int h = 0; h < H; ++h) { acc[h][0] = 0.f; acc[h][1] = 0.f; }

    for (int base = rp0; base < rp1; base += 64) {
        int i = base + lane;
        int lim = min(64, rp1 - base);
        if (i < rp1) {
            int s = csr[i];
            ssh[lane] = s;
            if (!small) {
                float e[H];
                if (H == 4) {
                    float4 lv = ((const float4*)ls)[s];
                    e[0] = lv.x; e[1] = lv.y; e[2] = lv.z; e[3] = lv.w;
                } else {
                    e[0] = ls[s];
                }
                #pragma unroll
                for (int h = 0; h < H; ++h) {
                    float v = e[h] + ldh[h];
                    v = (v > 0.f) ? v : 0.2f * v;
                    wsh[lane * H + h] = expf(v - m[h]) * inv[h];
                }
            }
        }
        __syncthreads();
        int t = 0;
        for (; t + 2 <= lim; t += 2) {
            int s0 = ssh[t], s1 = ssh[t + 1];
            const float* r0 = feat + (size_t)s0 * HID;
            const float* r1 = feat + (size_t)s1 * HID;
            float a0 = r0[lane], a1 = r1[lane];
            float b0 = 0.f, b1 = 0.f;
            if (lane < 8) { b0 = r0[64 + lane]; b1 = r1[64 + lane]; }
            #pragma unroll
            for (int h = 0; h < H; ++h) {
                float w0 = wsh[t * H + h], w1 = wsh[(t + 1) * H + h];
                acc[h][0] += w0 * a0 + w1 * a1;
                acc[h][1] += w0 * b0 + w1 * b1;
            }
        }
        if (t < lim) {
            int s0 = ssh[t];
            const float* r0 = feat + (size_t)s0 * HID;
            float a0 = r0[lane];
            float b0 = (lane < 8) ? r0[64 + lane] : 0.f;
            #pragma unroll
            for (int h = 0; h < H; ++h) {
                float w0 = wsh[t * H + h];
                acc[h][0] = fmaf(w0, a0, acc[h][0]);
                acc[h][1] = fmaf(w0, b0, acc[h][1]);
            }
        }
        __syncthreads();
    }

    // write out (+ optional bias/ELU/residual epilogue; EPI implies H==1)
    #pragma unroll
    for (int h = 0; h < H; ++h) {
        float v0 = acc[h][0], v1 = acc[h][1];
        if (EPI) {
            v0 += bias[lane];
            v0 = (v0 > 0.f) ? v0 : expm1f(v0);
            if (ADD_RES) v0 += res[(size_t)wid * HID + lane];
            if (lane < 8) {
                v1 += bias[64 + lane];
                v1 = (v1 > 0.f) ? v1 : expm1f(v1);
                if (ADD_RES) v1 += res[(size_t)wid * HID + 64 + lane];
            }
        }
        out[(size_t)wid * (H * HID) + h * HID + lane] = v0;
        if (lane < 8) out[(size_t)wid * (H * HID) + h * HID + 64 + lane] = v1;
    }
}

// ---------------------------------------------------------------------------
// Score MLP: out[n] = relu(h[n,:]@Ws1 + bs1) @ Ws2 + bs2.  32 lanes / node.
// ---------------------------------------------------------------------------
__global__ __launch_bounds__(256) void score_kernel(
        const float* __restrict__ h, const float* __restrict__ Ws1, const float* __restrict__ bs1,
        const float* __restrict__ Ws2, const float* __restrict__ bs2,
        float* __restrict__ out, int n) {
    int sub = threadIdx.x >> 5;
    int j = threadIdx.x & 31;
    int node = blockIdx.x * 8 + sub;
    if (node >= n) return;
    const float* row = h + (size_t)node * HID;
    float acc = bs1[j];
    #pragma unroll 8
    for (int c = 0; c < HID; ++c) acc = fmaf(row[c], Ws1[c * 32 + j], acc);
    float v = fmaxf(acc, 0.f) * Ws2[j];
    #pragma unroll
    for (int off = 16; off; off >>= 1) v += __shfl_down(v, off, 32);
    if (j == 0) out[node] = v + bs2[0];
}

// ---------------------------------------------------------------------------
extern "C" void kernel_launch(void* const* d_in, const int* in_sizes, int n_in,
                              void* d_out, int out_size, void* d_ws, size_t ws_size,
                              hipStream_t stream) {
    const float* x      = (const float*)d_in[0];
    const int*   ei     = (const int*)  d_in[1];
    const float* W_in   = (const float*)d_in[2];
    const float* b_in   = (const float*)d_in[3];
    const float* W1     = (const float*)d_in[4];
    const float* a_src1 = (const float*)d_in[5];
    const float* a_dst1 = (const float*)d_in[6];
    const float* b1     = (const float*)d_in[7];
    const float* W2     = (const float*)d_in[8];
    const float* a_src2 = (const float*)d_in[9];
    const float* a_dst2 = (const float*)d_in[10];
    const float* b2     = (const float*)d_in[11];
    const float* W3     = (const float*)d_in[12];
    const float* a_src3 = (const float*)d_in[13];
    const float* a_dst3 = (const float*)d_in[14];
    const float* b3     = (const float*)d_in[15];
    const float* Ws1    = (const float*)d_in[16];
    const float* bs1    = (const float*)d_in[17];
    const float* Ws2    = (const float*)d_in[18];
    const float* bs2    = (const float*)d_in[19];
    float* out = (float*)d_out;

    // workspace carve-up (all 4-byte elems)
    float* ws    = (float*)d_ws;
    float* x0    = ws;                        // N*72
    float* bufA  = x0 + (size_t)NN * HID;     // N*288 (agg1 / hp2 / hp3)
    float* bufB  = bufA + (size_t)NN * 288;   // N*288 (h1 / h2 / h3)
    float* ls    = bufB + (size_t)NN * 288;   // N*4
    float* ld    = ls + (size_t)NN * 4;       // N*4
    float* wsrc1 = ld + (size_t)NN * 4;       // 288
    float* wdst1 = wsrc1 + 288;               // 288
    int* deg    = (int*)(wdst1 + 288);
    int* rowptr = deg + NN;                   // N+1
    int* cursor = rowptr + NN + 1;            // N
    int* tmp    = cursor + NN;                // N (scan scratch)
    int* bsum   = tmp + NN;                   // 256
    int* csr    = bsum + 256;                 // ET

    hipMemsetAsync(deg, 0, NN * sizeof(int), stream);
    hipMemsetAsync(cursor, 0, NN * sizeof(int), stream);

    const int egrid = (ET + 255) / 256;
    const int sgrid = (NN + 255) / 256;       // 196
    hist_kernel<<<egrid, 256, 0, stream>>>(ei, deg);
    scan1_kernel<<<sgrid, 256, 0, stream>>>(deg, tmp, bsum, NN);
    scan2_kernel<<<1, 256, 0, stream>>>(bsum, sgrid);
    scan3_kernel<<<sgrid, 256, 0, stream>>>(tmp, bsum, rowptr, NN);
    scatter_kernel<<<egrid, 256, 0, stream>>>(ei, rowptr, cursor, csr);

    attnproj_kernel<<<2, 256, 0, stream>>>(W1, a_src1, a_dst1, wsrc1, wdst1);

    const int mblocks = (NN + BM - 1) / BM;   // 391
    // x0 = x @ W_in + b_in
    gemm_tile72<false, false><<<dim3(mblocks, 1), 256, 0, stream>>>(
        x, W_in, b_in, x0, NN, IN_DIM, IN_DIM, HID);
    // ---- layer 1 (aggregate in 72-dim input space, then per-head GEMM) ----
    logits1_kernel<<<NN, 64, 0, stream>>>(x0, wsrc1, wdst1, ls, ld, NN);
    agg_gather<4, false, false><<<NN, 64, 0, stream>>>(
        x0, ls, ld, rowptr, csr, nullptr, nullptr, bufA, NN);
    gemm_tile72<true, true><<<dim3(mblocks, 4), 256, 0, stream>>>(
        bufA, W1, b1, bufB, NN, HID, 288, 288);           // h1 = elu(agg@W1 + b1)
    // ---- layer 2 ----
    gemm_tile72<false, false><<<dim3(mblocks, 1), 256, 0, stream>>>(
        bufB, W2, nullptr, bufA, NN, 288, 288, HID);      // hp2
    logits_hp_kernel<<<(NN + 3) / 4, 256, 0, stream>>>(bufA, a_src2, a_dst2, ls, ld, NN);
    agg_gather<1, true, false><<<NN, 64, 0, stream>>>(
        bufA, ls, ld, rowptr, csr, b2, nullptr, bufB, NN);  // h2
    // ---- layer 3 ----
    gemm_tile72<false, false><<<dim3(mblocks, 1), 256, 0, stream>>>(
        bufB, W3, nullptr, bufA, NN, HID, HID, HID);      // hp3
    logits_hp_kernel<<<(NN + 3) / 4, 256, 0, stream>>>(bufA, a_src3, a_dst3, ls, ld, NN);
    agg_gather<1, true, true><<<NN, 64, 0, stream>>>(
        bufA, ls, ld, rowptr, csr, b3, x0, bufB, NN);     // h3 = elu(...)+x0
    // ---- score head ----
    score_kernel<<<(NN + 7) / 8, 256, 0, stream>>>(bufB, Ws1, bs1, Ws2, bs2, out, NN);
}

// Round 4
// 692.473 us; speedup vs baseline: 1.7378x; 1.2160x over previous
//
#include <hip/hip_runtime.h>
#include <cmath>

// Problem constants (match reference setup_inputs)
#define NN 50000
#define EE 800000
#define ET (EE + NN)   // edges + self loops
#define IN_DIM 256
#define HID 72

// ---------------------------------------------------------------------------
// CSR construction: histogram -> hierarchical scan -> scatter
// ---------------------------------------------------------------------------
__global__ void hist_kernel(const int* __restrict__ ei, int* __restrict__ deg) {
    int i = blockIdx.x * blockDim.x + threadIdx.x;
    if (i >= ET) return;
    int dst = (i < EE) ? ei[EE + i] : (i - EE);
    atomicAdd(&deg[dst], 1);
}

__global__ __launch_bounds__(256) void scan1_kernel(const int* __restrict__ deg,
        int* __restrict__ tmp, int* __restrict__ bsum, int n) {
    __shared__ int sh[256];
    int tid = threadIdx.x;
    int i = blockIdx.x * 256 + tid;
    sh[tid] = (i < n) ? deg[i] : 0;
    __syncthreads();
    for (int off = 1; off < 256; off <<= 1) {
        int t = (tid >= off) ? sh[tid - off] : 0;
        __syncthreads();
        sh[tid] += t;
        __syncthreads();
    }
    if (i < n) tmp[i] = sh[tid];
    if (tid == 255) bsum[blockIdx.x] = sh[255];
}

__global__ __launch_bounds__(256) void scan2_kernel(int* __restrict__ bsum, int nb) {
    __shared__ int sh[256];
    int tid = threadIdx.x;
    sh[tid] = (tid < nb) ? bsum[tid] : 0;
    __syncthreads();
    for (int off = 1; off < 256; off <<= 1) {
        int t = (tid >= off) ? sh[tid - off] : 0;
        __syncthreads();
        sh[tid] += t;
        __syncthreads();
    }
    if (tid < nb) bsum[tid] = sh[tid];
}

__global__ __launch_bounds__(256) void scan3_kernel(const int* __restrict__ tmp,
        const int* __restrict__ bsum, int* __restrict__ rowptr, int n) {
    int i = blockIdx.x * 256 + threadIdx.x;
    if (i == 0) rowptr[0] = 0;
    if (i < n) {
        int off = (blockIdx.x > 0) ? bsum[blockIdx.x - 1] : 0;
        rowptr[i + 1] = tmp[i] + off;
    }
}

__global__ void scatter_kernel(const int* __restrict__ ei, const int* __restrict__ rowptr,
                               int* __restrict__ cursor, int* __restrict__ csr) {
    int i = blockIdx.x * blockDim.x + threadIdx.x;
    if (i >= ET) return;
    int src = (i < EE) ? ei[i] : (i - EE);
    int dst = (i < EE) ? ei[EE + i] : (i - EE);
    int pos = atomicAdd(&cursor[dst], 1);
    csr[rowptr[dst] + pos] = src;
}

// ---------------------------------------------------------------------------
// Projected attention vectors for layer 1:
// wsrc[h][k] = sum_c W1[k, h*72+c] * a_src1[h,c]   (so logit_s = x0 . wsrc[h])
// ---------------------------------------------------------------------------
__global__ void attnproj_kernel(const float* __restrict__ W1,
                                const float* __restrict__ a_src, const float* __restrict__ a_dst,
                                float* __restrict__ wsrc, float* __restrict__ wdst) {
    int j = blockIdx.x * blockDim.x + threadIdx.x;   // j = h*72 + k
    if (j >= 4 * HID) return;
    int h = j / HID, k = j % HID;
    const float* wrow = W1 + (size_t)k * (4 * HID) + h * HID;
    const float* as = a_src + h * HID;
    const float* ad = a_dst + h * HID;
    float s = 0.f, d = 0.f;
    for (int c = 0; c < HID; ++c) {
        float w = wrow[c];
        s = fmaf(w, as[c], s);
        d = fmaf(w, ad[c], d);
    }
    wsrc[j] = s;
    wdst[j] = d;
}

// ---------------------------------------------------------------------------
// Tiled fp32 GEMM: C[M,Nfull] = A[M,K(+off)] @ B[K,Nfull] (+bias)(+ELU)
// BM=64 rows/block, 256 threads; thread (trow=tid>>3, tcol=tid&7) owns
// rows {trow, trow+32} x cols {tcol*9+j}.  Conflict-free LDS (broadcast x8).
// NLOGIT>0: fused attention-logit epilogue -> ls/ld[row*NLOGIT+h]
// (dot of the freshly computed 72-wide row with lvs/lvd, shfl-reduced over
// the 8 contiguous tcol lanes; only valid for grid.y==1 / Nfull==72).
// ---------------------------------------------------------------------------
#define BM 64
#define BK 32
template <bool BATCHED_A, bool ELU_EPI, int NLOGIT>
__global__ __launch_bounds__(256) void gemm_tile72(
        const float* __restrict__ A, const float* __restrict__ B,
        const float* __restrict__ bias, float* __restrict__ C,
        const float* __restrict__ lvs, const float* __restrict__ lvd,
        float* __restrict__ ls, float* __restrict__ ld,
        int M, int K, int lda, int Nfull) {
    __shared__ float As[BK][BM + 1];
    __shared__ float Bs[BK][72];
    int row0 = blockIdx.x * BM;
    int col0 = blockIdx.y * 72;
    int aoff = BATCHED_A ? col0 : 0;
    int tid = threadIdx.x;
    int trow = tid >> 3;    // 0..31
    int tcol = tid & 7;     // 0..7 (contiguous lanes share a row)
    float acc[2][9];
    #pragma unroll
    for (int i = 0; i < 2; ++i)
        #pragma unroll
        for (int j = 0; j < 9; ++j) acc[i][j] = 0.f;

    for (int k0 = 0; k0 < K; k0 += BK) {
        #pragma unroll
        for (int idx = tid; idx < BM * BK; idx += 256) {
            int r = idx / BK, kk = idx % BK;
            int gr = row0 + r, gk = k0 + kk;
            As[kk][r] = (gr < M && gk < K) ? A[(size_t)gr * lda + aoff + gk] : 0.f;
        }
        #pragma unroll
        for (int idx = tid; idx < BK * 72; idx += 256) {
            int kk = idx / 72, c = idx % 72;
            int gk = k0 + kk;
            Bs[kk][c] = (gk < K) ? B[(size_t)gk * Nfull + col0 + c] : 0.f;
        }
        __syncthreads();
        #pragma unroll 4
        for (int kk = 0; kk < BK; ++kk) {
            float a0 = As[kk][trow];
            float a1 = As[kk][trow + 32];
            float b[9];
            #pragma unroll
            for (int j = 0; j < 9; ++j) b[j] = Bs[kk][tcol * 9 + j];
            #pragma unroll
            for (int j = 0; j < 9; ++j) {
                acc[0][j] = fmaf(a0, b[j], acc[0][j]);
                acc[1][j] = fmaf(a1, b[j], acc[1][j]);
            }
        }
        __syncthreads();
    }

    #pragma unroll
    for (int i = 0; i < 2; ++i) {
        int gr = row0 + trow + 32 * i;   // uniform across the 8 tcol lanes
        float v[9];
        #pragma unroll
        for (int j = 0; j < 9; ++j) {
            int c = col0 + tcol * 9 + j;
            float t = acc[i][j] + (bias ? bias[c] : 0.f);
            if (ELU_EPI) t = (t > 0.f) ? t : expm1f(t);
            v[j] = t;
        }
        if (NLOGIT > 0) {
            #pragma unroll
            for (int h = 0; h < NLOGIT; ++h) {
                float s = 0.f, d = 0.f;
                #pragma unroll
                for (int j = 0; j < 9; ++j) {
                    int c = tcol * 9 + j;   // col0==0 when NLOGIT>0
                    s = fmaf(v[j], lvs[h * 72 + c], s);
                    d = fmaf(v[j], lvd[h * 72 + c], d);
                }
                s += __shfl_xor(s, 1); s += __shfl_xor(s, 2); s += __shfl_xor(s, 4);
                d += __shfl_xor(d, 1); d += __shfl_xor(d, 2); d += __shfl_xor(d, 4);
                if (tcol == 0 && gr < M) {
                    ls[gr * NLOGIT + h] = s;
                    ld[gr * NLOGIT + h] = d;
                }
            }
        }
        if (gr < M) {
            #pragma unroll
            for (int j = 0; j < 9; ++j)
                C[(size_t)gr * Nfull + col0 + tcol * 9 + j] = v[j];
        }
    }
}

// ---------------------------------------------------------------------------
// Softmax-weighted gather of 72-wide feature rows; one wave per dst node.
// ---------------------------------------------------------------------------
template <int H, bool EPI, bool ADD_RES>
__global__ __launch_bounds__(64) void agg_gather(
        const float* __restrict__ feat, const float* __restrict__ ls, const float* __restrict__ ld,
        const int* __restrict__ rowptr, const int* __restrict__ csr,
        const float* __restrict__ bias, const float* __restrict__ res,
        float* __restrict__ out, int n) {
    __shared__ float wsh[64 * H];
    __shared__ int ssh[64];
    int wid = blockIdx.x;
    int lane = threadIdx.x;
    if (wid >= n) return;
    int rp0 = rowptr[wid], rp1 = rowptr[wid + 1];
    bool small = (rp1 - rp0) <= 64;

    float ldh[H];
    if (H == 4) {
        float4 t = ((const float4*)ld)[wid];
        ldh[0] = t.x; ldh[1] = t.y; ldh[2] = t.z; ldh[3] = t.w;
    } else {
        ldh[0] = ld[wid];
    }

    // pass 1: per-head max of leaky-relu logits
    float m[H];
    #pragma unroll
    for (int h = 0; h < H; ++h) m[h] = -__builtin_inff();
    for (int i = rp0 + lane; i < rp1; i += 64) {
        int s = csr[i];
        float e[H];
        if (H == 4) {
            float4 lv = ((const float4*)ls)[s];
            e[0] = lv.x; e[1] = lv.y; e[2] = lv.z; e[3] = lv.w;
        } else {
            e[0] = ls[s];
        }
        #pragma unroll
        for (int h = 0; h < H; ++h) {
            float v = e[h] + ldh[h];
            v = (v > 0.f) ? v : 0.2f * v;
            m[h] = fmaxf(m[h], v);
        }
    }
    #pragma unroll
    for (int h = 0; h < H; ++h)
        #pragma unroll
        for (int off = 32; off; off >>= 1) m[h] = fmaxf(m[h], __shfl_xor(m[h], off));

    // pass 2: sum of exp (stash per-edge p for the common deg<=64 case)
    float ssum[H];
    #pragma unroll
    for (int h = 0; h < H; ++h) ssum[h] = 0.f;
    for (int i = rp0 + lane; i < rp1; i += 64) {
        int s = csr[i];
        float e[H];
        if (H == 4) {
            float4 lv = ((const float4*)ls)[s];
            e[0] = lv.x; e[1] = lv.y; e[2] = lv.z; e[3] = lv.w;
        } else {
            e[0] = ls[s];
        }
        #pragma unroll
        for (int h = 0; h < H; ++h) {
            float v = e[h] + ldh[h];
            v = (v > 0.f) ? v : 0.2f * v;
            float p = expf(v - m[h]);
            ssum[h] += p;
            wsh[lane * H + h] = p;
        }
    }
    #pragma unroll
    for (int h = 0; h < H; ++h)
        #pragma unroll
        for (int off = 32; off; off >>= 1) ssum[h] += __shfl_xor(ssum[h], off);
    float inv[H];
    #pragma unroll
    for (int h = 0; h < H; ++h) inv[h] = 1.f / fmaxf(ssum[h], 1e-16f);

    if (small && rp0 + lane < rp1) {
        #pragma unroll
        for (int h = 0; h < H; ++h) wsh[lane * H + h] *= inv[h];
    }

    // pass 3: weighted gather (2-edge unroll for latency overlap)
    float acc[H][2];
    #pragma unroll
    for (int h = 0; h < H; ++h) { acc[h][0] = 0.f; acc[h][1] = 0.f; }

    for (int base = rp0; base < rp1; base += 64) {
        int i = base + lane;
        int lim = min(64, rp1 - base);
        if (i < rp1) {
            int s = csr[i];
            ssh[lane] = s;
            if (!small) {
                float e[H];
                if (H == 4) {
                    float4 lv = ((const float4*)ls)[s];
                    e[0] = lv.x; e[1] = lv.y; e[2] = lv.z; e[3] = lv.w;
                } else {
                    e[0] = ls[s];
                }
                #pragma unroll
                for (int h = 0; h < H; ++h) {
                    float v = e[h] + ldh[h];
                    v = (v > 0.f) ? v : 0.2f * v;
                    wsh[lane * H + h] = expf(v - m[h]) * inv[h];
                }
            }
        }
        __syncthreads();
        int t = 0;
        for (; t + 2 <= lim; t += 2) {
            int s0 = ssh[t], s1 = ssh[t + 1];
            const float* r0 = feat + (size_t)s0 * HID;
            const float* r1 = feat + (size_t)s1 * HID;
            float a0 = r0[lane], a1 = r1[lane];
            float b0 = 0.f, b1 = 0.f;
            if (lane < 8) { b0 = r0[64 + lane]; b1 = r1[64 + lane]; }
            #pragma unroll
            for (int h = 0; h < H; ++h) {
                float w0 = wsh[t * H + h], w1 = wsh[(t + 1) * H + h];
                acc[h][0] += w0 * a0 + w1 * a1;
                acc[h][1] += w0 * b0 + w1 * b1;
            }
        }
        if (t < lim) {
            int s0 = ssh[t];
            const float* r0 = feat + (size_t)s0 * HID;
            float a0 = r0[lane];
            float b0 = (lane < 8) ? r0[64 + lane] : 0.f;
            #pragma unroll
            for (int h = 0; h < H; ++h) {
                float w0 = wsh[t * H + h];
                acc[h][0] = fmaf(w0, a0, acc[h][0]);
                acc[h][1] = fmaf(w0, b0, acc[h][1]);
            }
        }
        __syncthreads();
    }

    // write out (+ optional bias/ELU/residual epilogue; EPI implies H==1)
    #pragma unroll
    for (int h = 0; h < H; ++h) {
        float v0 = acc[h][0], v1 = acc[h][1];
        if (EPI) {
            v0 += bias[lane];
            v0 = (v0 > 0.f) ? v0 : expm1f(v0);
            if (ADD_RES) v0 += res[(size_t)wid * HID + lane];
            if (lane < 8) {
                v1 += bias[64 + lane];
                v1 = (v1 > 0.f) ? v1 : expm1f(v1);
                if (ADD_RES) v1 += res[(size_t)wid * HID + 64 + lane];
            }
        }
        out[(size_t)wid * (H * HID) + h * HID + lane] = v0;
        if (lane < 8) out[(size_t)wid * (H * HID) + h * HID + 64 + lane] = v1;
    }
}

// ---------------------------------------------------------------------------
// Score MLP: out[n] = relu(h[n,:]@Ws1 + bs1) @ Ws2 + bs2.  32 lanes / node.
// ---------------------------------------------------------------------------
__global__ __launch_bounds__(256) void score_kernel(
        const float* __restrict__ h, const float* __restrict__ Ws1, const float* __restrict__ bs1,
        const float* __restrict__ Ws2, const float* __restrict__ bs2,
        float* __restrict__ out, int n) {
    int sub = threadIdx.x >> 5;
    int j = threadIdx.x & 31;
    int node = blockIdx.x * 8 + sub;
    if (node >= n) return;
    const float* row = h + (size_t)node * HID;
    float acc = bs1[j];
    #pragma unroll 8
    for (int c = 0; c < HID; ++c) acc = fmaf(row[c], Ws1[c * 32 + j], acc);
    float v = fmaxf(acc, 0.f) * Ws2[j];
    #pragma unroll
    for (int off = 16; off; off >>= 1) v += __shfl_down(v, off, 32);
    if (j == 0) out[node] = v + bs2[0];
}

// ---------------------------------------------------------------------------
extern "C" void kernel_launch(void* const* d_in, const int* in_sizes, int n_in,
                              void* d_out, int out_size, void* d_ws, size_t ws_size,
                              hipStream_t stream) {
    const float* x      = (const float*)d_in[0];
    const int*   ei     = (const int*)  d_in[1];
    const float* W_in   = (const float*)d_in[2];
    const float* b_in   = (const float*)d_in[3];
    const float* W1     = (const float*)d_in[4];
    const float* a_src1 = (const float*)d_in[5];
    const float* a_dst1 = (const float*)d_in[6];
    const float* b1     = (const float*)d_in[7];
    const float* W2     = (const float*)d_in[8];
    const float* a_src2 = (const float*)d_in[9];
    const float* a_dst2 = (const float*)d_in[10];
    const float* b2     = (const float*)d_in[11];
    const float* W3     = (const float*)d_in[12];
    const float* a_src3 = (const float*)d_in[13];
    const float* a_dst3 = (const float*)d_in[14];
    const float* b3     = (const float*)d_in[15];
    const float* Ws1    = (const float*)d_in[16];
    const float* bs1    = (const float*)d_in[17];
    const float* Ws2    = (const float*)d_in[18];
    const float* bs2    = (const float*)d_in[19];
    float* out = (float*)d_out;

    // workspace carve-up (all 4-byte elems)
    float* ws    = (float*)d_ws;
    float* x0    = ws;                        // N*72
    float* bufA  = x0 + (size_t)NN * HID;     // N*288 (agg1 / hp2 / hp3)
    float* bufB  = bufA + (size_t)NN * 288;   // N*288 (h1 / h2 / h3)
    float* ls    = bufB + (size_t)NN * 288;   // N*4
    float* ld    = ls + (size_t)NN * 4;       // N*4
    float* wsrc1 = ld + (size_t)NN * 4;       // 288
    float* wdst1 = wsrc1 + 288;               // 288
    int* deg    = (int*)(wdst1 + 288);
    int* rowptr = deg + NN;                   // N+1
    int* cursor = rowptr + NN + 1;            // N
    int* tmp    = cursor + NN;                // N (scan scratch)
    int* bsum   = tmp + NN;                   // 256
    int* csr    = bsum + 256;                 // ET

    hipMemsetAsync(deg, 0, NN * sizeof(int), stream);
    hipMemsetAsync(cursor, 0, NN * sizeof(int), stream);

    const int egrid = (ET + 255) / 256;
    const int sgrid = (NN + 255) / 256;       // 196
    hist_kernel<<<egrid, 256, 0, stream>>>(ei, deg);
    scan1_kernel<<<sgrid, 256, 0, stream>>>(deg, tmp, bsum, NN);
    scan2_kernel<<<1, 256, 0, stream>>>(bsum, sgrid);
    scan3_kernel<<<sgrid, 256, 0, stream>>>(tmp, bsum, rowptr, NN);
    scatter_kernel<<<egrid, 256, 0, stream>>>(ei, rowptr, cursor, csr);

    attnproj_kernel<<<2, 256, 0, stream>>>(W1, a_src1, a_dst1, wsrc1, wdst1);

    const int mblocks = (NN + BM - 1) / BM;   // 782
    // x0 = x @ W_in + b_in, fused layer-1 logits (H=4 via projected vectors)
    gemm_tile72<false, false, 4><<<dim3(mblocks, 1), 256, 0, stream>>>(
        x, W_in, b_in, x0, wsrc1, wdst1, ls, ld, NN, IN_DIM, IN_DIM, HID);
    // ---- layer 1 (aggregate in 72-dim input space, then per-head GEMM) ----
    agg_gather<4, false, false><<<NN, 64, 0, stream>>>(
        x0, ls, ld, rowptr, csr, nullptr, nullptr, bufA, NN);
    gemm_tile72<true, true, 0><<<dim3(mblocks, 4), 256, 0, stream>>>(
        bufA, W1, b1, bufB, nullptr, nullptr, nullptr, nullptr, NN, HID, 288, 288);
    // ---- layer 2 ----
    gemm_tile72<false, false, 1><<<dim3(mblocks, 1), 256, 0, stream>>>(
        bufB, W2, nullptr, bufA, a_src2, a_dst2, ls, ld, NN, 288, 288, HID);
    agg_gather<1, true, false><<<NN, 64, 0, stream>>>(
        bufA, ls, ld, rowptr, csr, b2, nullptr, bufB, NN);
    // ---- layer 3 ----
    gemm_tile72<false, false, 1><<<dim3(mblocks, 1), 256, 0, stream>>>(
        bufB, W3, nullptr, bufA, a_src3, a_dst3, ls, ld, NN, HID, HID, HID);
    agg_gather<1, true, true><<<NN, 64, 0, stream>>>(
        bufA, ls, ld, rowptr, csr, b3, x0, bufB, NN);
    // ---- score head ----
    score_kernel<<<(NN + 7) / 8, 256, 0, stream>>>(bufB, Ws1, bs1, Ws2, bs2, out, NN);
}